// Round 10
// baseline (783.869 us; speedup 1.0000x reference)
//
#include <hip/hip_runtime.h>
#include <hip/hip_bf16.h>

typedef __bf16  bf16x8 __attribute__((ext_vector_type(8)));
typedef float   f32x4  __attribute__((ext_vector_type(4)));

// global->LDS async, 16B/lane. _C: fully cached (immutable X stream).
// _H: sc0 = bypass L1, allocate L2 (h panels; freshness via 12-deep slot
// rotation + aligned fence every 8 phases -- proven R7).
#define GLOAD16_C(gptr, lptr) \
  __builtin_amdgcn_global_load_lds((const __attribute__((address_space(1))) void*)(gptr), \
                                   (__attribute__((address_space(3))) void*)(lptr), 16, 0, 0)
#define GLOAD16_H(gptr, lptr) \
  __builtin_amdgcn_global_load_lds((const __attribute__((address_space(1))) void*)(gptr), \
                                   (__attribute__((address_space(3))) void*)(lptr), 16, 0, 0x1)

#define WAIT_VM10  asm volatile("s_waitcnt vmcnt(10)" ::: "memory")
#define WAIT_VM8   asm volatile("s_waitcnt vmcnt(8)"  ::: "memory")
#define WAIT_VM6   asm volatile("s_waitcnt vmcnt(6)"  ::: "memory")
#define WAIT_VM4   asm volatile("s_waitcnt vmcnt(4)"  ::: "memory")
#define WAIT_VM2   asm volatile("s_waitcnt vmcnt(2)"  ::: "memory")
#define WAIT_VM0   asm volatile("s_waitcnt vmcnt(0)"  ::: "memory")

__device__ __forceinline__ void wait_vm_chunks(int n) {   // n chunks (2 vm each) may stay outstanding
  if      (n <= 0) WAIT_VM0;
  else if (n == 1) WAIT_VM2;
  else if (n == 2) WAIT_VM4;
  else if (n == 3) WAIT_VM6;
  else if (n == 4) WAIT_VM8;
  else             WAIT_VM10;
}
__device__ __forceinline__ void wait_lgkm_n(int n) {
  if      (n <= 0) asm volatile("s_waitcnt lgkmcnt(0)" ::: "memory");
  else if (n <= 2) asm volatile("s_waitcnt lgkmcnt(2)" ::: "memory");
  else             asm volatile("s_waitcnt lgkmcnt(6)" ::: "memory");
}

__device__ __forceinline__ float sigm(float x)  { return 1.0f / (1.0f + __expf(-x)); }
__device__ __forceinline__ float tanhp(float x) { return 2.0f / (1.0f + __expf(-2.0f * x)) - 1.0f; }

// LLC-coherent scalar load / stores (bypass L1/L2)
__device__ __forceinline__ unsigned int coh_load(const unsigned int* p) {
  unsigned int v;
  asm volatile("global_load_dword %0, %1, off sc0 sc1\n\ts_waitcnt vmcnt(0)"
               : "=v"(v) : "v"(p) : "memory");
  return v;
}
__device__ __forceinline__ int coh_load_i(const int* p) {
  int v;
  asm volatile("global_load_dword %0, %1, off sc0 sc1\n\ts_waitcnt vmcnt(0)"
               : "=v"(v) : "v"(p) : "memory");
  return v;
}
__device__ __forceinline__ void coh_store16(void* p, bf16x8 v) {
  f32x4 f = *(f32x4*)&v;
  asm volatile("global_store_dwordx4 %0, %1, off sc0 sc1" :: "v"(p), "v"(f) : "memory");
}
__device__ __forceinline__ void flag_store(int* fp, int v) {
  asm volatile("global_store_dword %0, %1, off sc0 sc1" :: "v"(fp), "v"(v) : "memory");
}

#define TSTEPS 80
#define BATCH  512
#define EDIM   256
#define HDIM   512
#define K2     1024
#define K1     768
#define NCH    16           // absolute B K-chunks in registers (split by K-parity: 8/wave)
#define NCHW   8            // breg chunks per wave
#define RS     12           // ring slots (even -> preserves chunk-parity mapping)
#define D_SLOTS 12
#define SLOT_BYTES 524544   // 512 KB + 256 B guard
// LDS: BsL (16 chunks * 4KB = 64KB) | ring (12 * 8KB = 96KB) = exactly 160KiB.
// red (32KB f32 partial-acc) and epi (6KB) ALIAS dead ring slots at epilogue.
#define RING_OFF 65536
#define RED_OFF  65536
#define EPI_OFF  98304
#define EPI_STR  24
#define LDS_BYTES 163840

struct Params {
  const __hip_bfloat16* Wz1t;   // [2048][768]  bf16, [N'][K], K-order [W1|U1] (x first)
  const __hip_bfloat16* Wz2t;   // [2048][1024]             K-order [W2|U2] (h1 first)
  const float* bz1;             // [2048] permuted
  const float* bz2;
  const __hip_bfloat16* Xall;   // [80][512][256] bf16
  char* h1base;                 // 12 slots, SLOT_BYTES stride
  char* h2base;                 // 12 slots
  int* flags;                   // 256 entries, 16B stride: z1 at idx, z2 at 128+idx
  const float* Wfc; const float* bfc;
  float* out;
};

// ---------------- prep kernels ----------------
// permuted column: n' = ntile*64 + gate*16 + u  (ntile = j>>4, u = j&15)
// K-order: the TIGHT-gated operand goes LAST:
//   Wz1t: k<256 -> W1[k] (x),  k>=256 -> U1[k-256] (h1[s-1], peer-gated)
//   Wz2t: k<512 -> W2[k] (h1), k>=512 -> U2[k-512] (h2[s-1], peer-gated)

__global__ __launch_bounds__(256) void prep_weights(
    const float* __restrict__ W1, const float* __restrict__ U1, const float* __restrict__ b1,
    const float* __restrict__ W2, const float* __restrict__ U2, const float* __restrict__ b2,
    __hip_bfloat16* __restrict__ Wz1t, __hip_bfloat16* __restrict__ Wz2t,
    float* __restrict__ bz1, float* __restrict__ bz2) {
  long idx = (long)blockIdx.x * 256 + threadIdx.x;
  const long n1 = 2048L * K1, n2 = 2048L * K2;
  if (idx < n1) {
    int n = (int)(idx / K1), k = (int)(idx % K1);
    int col = ((n >> 4) & 3) * 512 + (n >> 6) * 16 + (n & 15);
    float v = (k < 256) ? W1[(size_t)k * 2048 + col] : U1[(size_t)(k - 256) * 2048 + col];
    Wz1t[idx] = __float2bfloat16(v);
  } else if (idx < n1 + n2) {
    long r = idx - n1;
    int n = (int)(r / K2), k = (int)(r % K2);
    int col = ((n >> 4) & 3) * 512 + (n >> 6) * 16 + (n & 15);
    float v = (k < 512) ? W2[(size_t)k * 2048 + col] : U2[(size_t)(k - 512) * 2048 + col];
    Wz2t[r] = __float2bfloat16(v);
  } else if (idx < n1 + n2 + 2048) {
    int n = (int)(idx - (n1 + n2));
    bz1[n] = b1[((n >> 4) & 3) * 512 + (n >> 6) * 16 + (n & 15)];
  } else if (idx < n1 + n2 + 4096) {
    int n = (int)(idx - (n1 + n2 + 2048));
    bz2[n] = b2[((n >> 4) & 3) * 512 + (n >> 6) * 16 + (n & 15)];
  }
}

__global__ __launch_bounds__(256) void prep_gather(
    const int* __restrict__ tokens, const float* __restrict__ emb,
    __hip_bfloat16* __restrict__ Xall, float4* __restrict__ zp, int zn) {
  int idx = blockIdx.x * 256 + threadIdx.x;
  if (idx < zn) zp[idx] = make_float4(0.f, 0.f, 0.f, 0.f);   // zero state+flags
  int e  = (idx & 63) * 4;
  int rb = idx >> 6;            // t*512 + b
  int t  = rb >> 9;
  int b  = rb & 511;
  int tok = tokens[b * TSTEPS + t];
  const float4 v = *(const float4*)&emb[(size_t)tok * EDIM + e];
  __hip_bfloat16* o = Xall + (size_t)rb * EDIM + e;
  o[0] = __float2bfloat16(v.x); o[1] = __float2bfloat16(v.y);
  o[2] = __float2bfloat16(v.z); o[3] = __float2bfloat16(v.w);
}

// ---------------- main kernel ----------------
// R16 = R10's inter-block protocol (gates/targets/fences/tail byte-identical,
// proven 610us) + ONE structural delta: 512 threads/block = 8 waves = 2
// waves/SIMD (TLP). Counters showed ~50% idle at 1 wave/SIMD (MfmaUtil 21 +
// VALUBusy 28, HBM 3.5%): every waitcnt stall was dead time. R13/R14/R15
// falsified window-depth / transport / LDS-volume models -- the stall is
// unfilled issue slots, fixed only by a second wave per SIMD.
// Decomposition: wave (wr,wk)=(tid>>7, (tid>>6)&1) computes chunks kc==wk
// (mod 2) for rows [wr*32,+32): staging stays WAVE-LOCAL (per-wave vmcnt
// discipline unchanged), LDS traffic/step unchanged, per-wave prefetch cover
// doubles (wave cadence halves). breg: 8 chunks/wave (128 VGPR; total ~245
// <= 256 = 2-waves/SIMD budget, enforced by __launch_bounds__(512,2)).
// Ring 12 slots (even modulus preserves parity). Partial-acc reduction
// wk0 -> LDS(32KB f32, aliases dead ring slots) -> wk1 adds, then wk1 does
// the R10 epilogue verbatim. Barriers order red/epi aliasing vs ring reuse.

__device__ __forceinline__ void gate_wave(const int* flags, int base1, int t1,
                                          int base2, int t2, int lane) {
  const int idx = lane & 31;
  const int* fp = flags + (((lane < 32) ? base1 : base2) + idx) * 4;   // 16B stride
  const int tgt = (lane < 32) ? t1 : t2;
  for (;;) {
    int v = coh_load_i(fp);
    if (__ballot(v >= tgt) == ~0ull) break;
    __builtin_amdgcn_s_sleep(2);
  }
}

// per-wave K-loop over wave-chunks i (abs chunk kc = K0 + 2i + wk), L=LEN/2.
// Lookahead 5 wave-chunks (6 parity-slots in the 12-ring); steady-state wait
// allows 3 outstanding. stage(i+5) targets slot of wave-chunk i-1, whose
// ds_reads (issued iter i-2) retired at iter i-1's lgkm wait.
template<int K0, int LEN, int STRIDE, bool COH>
__device__ __forceinline__ void run_part(
    const __hip_bfloat16* __restrict__ Asrc, int m0, int wr, int wk, int lane,
    __hip_bfloat16* __restrict__ ring, const __hip_bfloat16* __restrict__ BsL,
    const bf16x8 (&breg)[NCHW][4], const int (&aoff)[2], const int (&boff)[4],
    f32x4 (&acc)[2][4]) {
  constexpr int L = LEN / 2;
  constexpr int FILLW = (L < 5) ? L : 5;
  auto stage = [&](int i) {
    const int so = ((K0 + 2 * i) % RS);               // + wk at use (parity slot)
#pragma unroll
    for (int it = 0; it < 2; ++it) {
      const int gbase = wr * 128 + it * 64;
      const int g   = gbase + lane;
      const int row = g >> 2;
      const int gc  = (g & 3) ^ ((row >> 1) & 3);     // XOR swizzle
      __hip_bfloat16* lp = ring + (so + wk) * 4096 + gbase * 8;
      const __hip_bfloat16* gp = Asrc + (size_t)(m0 + row) * STRIDE + (2 * i + wk) * 32 + gc * 8;
      if (COH) GLOAD16_H(gp, lp); else GLOAD16_C(gp, lp);
    }
  };
#pragma unroll
  for (int f = 0; f < FILLW; ++f) stage(f);

  bf16x8 af[2][2], bf[2][4];
  wait_vm_chunks(FILLW - 1);                          // wave-chunk 0 resident
#pragma unroll
  for (int mi = 0; mi < 2; ++mi)
    af[0][mi] = *(const bf16x8*)(ring + ((K0 % RS) + wk) * 4096 + aoff[mi]);
  if (K0 + 1 >= NCH) {                                // kc0 = K0+wk >= NCH (folds)
#pragma unroll
    for (int g = 0; g < 4; ++g)
      bf[0][g] = *(const bf16x8*)(BsL + (K0 + wk - NCH) * 2048 + boff[g]);
  }

#pragma unroll
  for (int i = 0; i < L; ++i) {
    const int cur = i & 1, nxt = cur ^ 1;
    if (i + 1 < L) {
      wait_vm_chunks(L - 2 - i < 3 ? L - 2 - i : 3);  // wave-chunk i+1 resident
#pragma unroll
      for (int mi = 0; mi < 2; ++mi)
        af[nxt][mi] = *(const bf16x8*)(ring + (((K0 + 2 * (i + 1)) % RS) + wk) * 4096 + aoff[mi]);
      if (K0 + 2 * (i + 1) + 1 >= NCH) {              // kn may hit BsL (folds per i)
#pragma unroll
        for (int g = 0; g < 4; ++g)
          bf[nxt][g] = *(const bf16x8*)(BsL + (K0 + 2 * (i + 1) + wk - NCH) * 2048 + boff[g]);
        wait_lgkm_n(6);                 // frags of wave-chunk i done
      } else {
        wait_lgkm_n(2);
      }
      if (i + FILLW < L) stage(i + FILLW);
    } else {
      wait_lgkm_n(0);
    }
#pragma unroll
    for (int mi = 0; mi < 2; ++mi)
#pragma unroll
      for (int g = 0; g < 4; ++g)
        acc[mi][g] = __builtin_amdgcn_mfma_f32_16x16x32_bf16(
            af[cur][mi],
            (K0 + 2 * i + 1 < NCH ? breg[((K0 >> 1) + i) & (NCHW - 1)][g] : bf[cur][g]),
            acc[mi][g], 0, 0, 0);
  }
}

template<bool Z2>
__device__ __forceinline__ void role_loop(const Params& p, char* smem, int tid,
                                          int grp, int ntile) {
  constexpr int K   = Z2 ? K2 : K1;
  constexpr int NC  = K / 32;
  const int lane = tid & 63;
  const int w    = tid >> 6;           // 0..7
  const int wk   = w & 1;              // K-parity group
  const int wr   = w >> 1;             // row group (32 rows)
  const int q    = lane >> 4;
  const int m16  = lane & 15;
  const int m0   = grp * 128;
  const int n0   = ntile * 64;

  __hip_bfloat16* BsL  = (__hip_bfloat16*)smem;
  __hip_bfloat16* ring = (__hip_bfloat16*)(smem + RING_OFF);
  __hip_bfloat16* epi  = (__hip_bfloat16*)(smem + EPI_OFF);

  const __hip_bfloat16* Bg = (Z2 ? p.Wz2t : p.Wz1t) + (size_t)n0 * K;

  // one-time: wave's B chunks (2j+wk, j<8) into registers (static indexing)
  bf16x8 breg[NCHW][4];
#pragma unroll
  for (int j = 0; j < NCHW; ++j)
#pragma unroll
    for (int g = 0; g < 4; ++g)
      breg[j][g] = *(const bf16x8*)(Bg + (size_t)(g * 16 + m16) * K + (2 * j + wk) * 32 + q * 8);

  // one-time: B chunks NCH..NC-1 into LDS, chunk-major granule-swizzled
  for (int it0 = tid; it0 < (NC - NCH) * 256; it0 += 512) {
    int cid = it0 >> 8, gg = it0 & 255;
    int r = gg >> 2, c8 = gg & 3;
    int sw = c8 ^ ((r >> 1) & 3);
    *(bf16x8*)(BsL + cid * 2048 + r * 32 + sw * 8) =
        *(const bf16x8*)(Bg + (size_t)r * K + (NCH + cid) * 32 + c8 * 8);
  }
  const float* bias = Z2 ? p.bz2 : p.bz1;
  float bz[4];
#pragma unroll
  for (int g = 0; g < 4; ++g) bz[g] = bias[n0 + g * 16 + m16];

  const int swz = (q ^ ((m16 >> 1) & 3)) * 8;
  int aoff[2], boff[4];
#pragma unroll
  for (int mi = 0; mi < 2; ++mi) aoff[mi] = (wr * 32 + mi * 16 + m16) * 32 + swz;
#pragma unroll
  for (int g = 0; g < 4; ++g)    boff[g]  = (g * 16 + m16) * 32 + swz;

  float cst[2][4] = {{0.f,0.f,0.f,0.f},{0.f,0.f,0.f,0.f}};   // live in wk=1 waves
  const int fself = (Z2 ? 128 : 0) + grp * 32 + ntile;
  const int jbase = ntile * 16;
  __syncthreads();

  // pre-loop: z2's slack gate for step 0 (z1 >= 1 -> h1[0] committed)
  if (Z2) {
    if (w == 0) gate_wave(p.flags, grp * 32, 1, grp * 32, 1, lane);
    __syncthreads();
  }

  for (int s = 0; s < TSTEPS; ++s) {
    const int sl = s % D_SLOTS, slp = (s + D_SLOTS - 1) % D_SLOTS;
    const __hip_bfloat16* Aa = Z2
        ? (const __hip_bfloat16*)(p.h1base + (size_t)sl * SLOT_BYTES)    // h1[s]
        : p.Xall + (size_t)s * BATCH * EDIM;                             // x[s]
    const __hip_bfloat16* Ab = Z2
        ? (const __hip_bfloat16*)(p.h2base + (size_t)slp * SLOT_BYTES)   // h2[s-1]
        : (const __hip_bfloat16*)(p.h1base + (size_t)slp * SLOT_BYTES);  // h1[s-1]
    __hip_bfloat16* hout = (__hip_bfloat16*)
        ((Z2 ? p.h2base : p.h1base) + (size_t)sl * SLOT_BYTES);

    f32x4 acc[2][4];
#pragma unroll
    for (int mi = 0; mi < 2; ++mi)
#pragma unroll
      for (int g = 0; g < 4; ++g) {
        const float b = wk ? bz[g] : 0.f;            // bias once (wk=1 holds it)
        acc[mi][g] = (f32x4){b, b, b, b};
      }

    // ---- part A (z2 slack gate already satisfied in previous tail) ----
    if (Z2) run_part<0, 16, 512, true >(Aa, m0, wr, wk, lane, ring, BsL, breg, aoff, boff, acc);
    else    run_part<0,  8, 256, false>(Aa, m0, wr, wk, lane, ring, BsL, breg, aoff, boff, acc);

    // ---- part B gate (tight peer RAW, hidden behind part A) + fence ----
    if (w == 0) {
      if (Z2) gate_wave(p.flags, 128 + grp * 32, s, 128 + grp * 32, s, lane);
      else    gate_wave(p.flags, grp * 32, s, 128 + grp * 32, s - (D_SLOTS - 1), lane);
      if ((s & 7) == 0) __builtin_amdgcn_fence(__ATOMIC_ACQUIRE, "agent");
    }
    __syncthreads();
    if (Z2) run_part<16, 16, 512, true>(Ab, m0, wr, wk, lane, ring, BsL, breg, aoff, boff, acc);
    else    run_part< 8, 16, 512, true>(Ab, m0, wr, wk, lane, ring, BsL, breg, aoff, boff, acc);

    // ---- epilogue: reduce wk pairs via LDS (aliases dead ring), then gates ----
    __syncthreads();                               // all waves' ring reads done
    if (!wk) {
      float* red = (float*)(smem + RED_OFF);
#pragma unroll
      for (int mi = 0; mi < 2; ++mi)
#pragma unroll
        for (int g = 0; g < 4; ++g)
          *(f32x4*)(red + wr * 2048 + (mi * 4 + g) * 256 + lane * 4) = acc[mi][g];
    }
    __syncthreads();
    if (wk) {
      const float* red = (const float*)(smem + RED_OFF);
#pragma unroll
      for (int mi = 0; mi < 2; ++mi)
#pragma unroll
        for (int g = 0; g < 4; ++g)
          acc[mi][g] += *(const f32x4*)(red + wr * 2048 + (mi * 4 + g) * 256 + lane * 4);
#pragma unroll
      for (int mi = 0; mi < 2; ++mi)
#pragma unroll
        for (int rr = 0; rr < 4; ++rr) {
          const float zi = acc[mi][0][rr], zf = acc[mi][1][rr];
          const float zg = acc[mi][2][rr], zo = acc[mi][3][rr];
          const float cn = sigm(zf) * cst[mi][rr] + sigm(zi) * tanhp(zg);
          cst[mi][rr] = cn;
          epi[(wr * 32 + mi * 16 + q * 4 + rr) * EPI_STR + m16] = __float2bfloat16(sigm(zo) * tanhp(cn));
        }
    }
    __syncthreads();
    if (wk) {
      const int idx = wr * 64 + lane;              // 0..255
      const int r = idx >> 1, hf = idx & 1;
      bf16x8 hv = *(const bf16x8*)(epi + r * EPI_STR + hf * 8);
      coh_store16(hout + (size_t)(m0 + r) * HDIM + jbase + hf * 8, hv);
    }
    // z2: next step's slack gate polls here (w0 = wk0: overlaps wk1's store
    // drain). z1 lead >= 2 in steady state.
    if (Z2 && w == 0 && s + 1 < TSTEPS)
      gate_wave(p.flags, grp * 32, s + 2, grp * 32, s + 2, lane);
    WAIT_VM0;                                      // each wave drains its own
    __syncthreads();
    if (tid == 0) flag_store(p.flags + fself * 4, s + 1);
  }
}

__global__ __launch_bounds__(512, 2) void lstm_seq(Params p) {
  extern __shared__ char smem[];
  const int tid = threadIdx.x;
  const bool z2  = ((blockIdx.x & 1) == 0);
  const int grp  = (blockIdx.x >> 1) & 3;
  const int ntile = blockIdx.x >> 3;

  if (z2) role_loop<true>(p, smem, tid, grp, ntile);
  else    role_loop<false>(p, smem, tid, grp, ntile);

  // final FC: block b -> rows {2b, 2b+1}; wait on producing z2 group's flags
  const int lane = tid & 63, w = tid >> 6;
  if (w == 0) {
    const int g2 = blockIdx.x >> 6;
    gate_wave(p.flags, 128 + g2 * 32, TSTEPS, 128 + g2 * 32, TSTEPS, lane);
  }
  __syncthreads();
  if (w < 2) {
    const int row = blockIdx.x * 2 + w;
    const unsigned int* hp = (const unsigned int*)
        (p.h2base + (size_t)((TSTEPS - 1) % D_SLOTS) * SLOT_BYTES) + (size_t)row * (HDIM / 2);
    float sum = 0.f;
#pragma unroll
    for (int cc = 0; cc < 4; ++cc) {
      unsigned int d = coh_load(hp + lane * 4 + cc);
      union { unsigned int ui; float f; } lo, hi;
      lo.ui = d << 16; hi.ui = d & 0xffff0000u;
      sum += lo.f * p.Wfc[(lane * 4 + cc) * 2] + hi.f * p.Wfc[(lane * 4 + cc) * 2 + 1];
    }
#pragma unroll
    for (int o = 32; o > 0; o >>= 1) sum += __shfl_down(sum, o, 64);
    if (lane == 0) p.out[row] = sigm(sum + p.bfc[0]);
  }
}

// ---------------- host launcher ----------------

extern "C" void kernel_launch(void* const* d_in, const int* in_sizes, int n_in,
                              void* d_out, int out_size, void* d_ws, size_t ws_size,
                              hipStream_t stream) {
  const int*   tokens = (const int*)d_in[0];
  const float* emb = (const float*)d_in[1];
  const float* W1  = (const float*)d_in[2];
  const float* U1  = (const float*)d_in[3];
  const float* b1  = (const float*)d_in[4];
  const float* W2  = (const float*)d_in[5];
  const float* U2  = (const float*)d_in[6];
  const float* b2  = (const float*)d_in[7];
  const float* Wfc = (const float*)d_in[8];
  const float* bfc = (const float*)d_in[9];

  char* ws = (char*)d_ws;
  size_t off = 0;
  auto alloc = [&](size_t bytes) {
    char* r = ws + off;
    off += (bytes + 255) & ~(size_t)255;
    return r;
  };
  __hip_bfloat16* Wz1t = (__hip_bfloat16*)alloc(2048UL * K1 * 2);
  __hip_bfloat16* Wz2t = (__hip_bfloat16*)alloc(2048UL * K2 * 2);
  float* bz1 = (float*)alloc(2048 * 4);
  float* bz2 = (float*)alloc(2048 * 4);
  __hip_bfloat16* Xall = (__hip_bfloat16*)alloc((size_t)TSTEPS * BATCH * EDIM * 2);
  // state: 24 h-slots (12 h1 + 12 h2) + flags (4096B), ALL zeroed in prep_gather
  const size_t state_bytes = 24UL * SLOT_BYTES + 4096;   // 12,593,152
  char* state = alloc(state_bytes);

  Params prm;
  prm.h1base = state;
  prm.h2base = state + 12UL * SLOT_BYTES;
  prm.flags  = (int*)(state + 24UL * SLOT_BYTES);

  prep_weights<<<dim3(14352), dim3(256), 0, stream>>>(W1, U1, b1, W2, U2, b2, Wz1t, Wz2t, bz1, bz2);
  prep_gather<<<dim3(10240), dim3(256), 0, stream>>>(tokens, emb, Xall,
                                                     (float4*)state, (int)(state_bytes / 16));

  hipFuncSetAttribute((const void*)lstm_seq,
                      hipFuncAttributeMaxDynamicSharedMemorySize, LDS_BYTES);

  prm.Wz1t = Wz1t; prm.Wz2t = Wz2t; prm.bz1 = bz1; prm.bz2 = bz2;
  prm.Xall = Xall;
  prm.Wfc = Wfc; prm.bfc = bfc;
  prm.out = (float*)d_out;

  lstm_seq<<<dim3(256), dim3(512), LDS_BYTES, stream>>>(prm);
}

// Round 11
// 737.420 us; speedup vs baseline: 1.0630x; 1.0630x over previous
//
#include <hip/hip_runtime.h>
#include <hip/hip_bf16.h>

typedef __bf16  bf16x8 __attribute__((ext_vector_type(8)));
typedef float   f32x4  __attribute__((ext_vector_type(4)));

// global->LDS async, 16B/lane. _C: fully cached (immutable X stream).
// _H: sc0 = bypass L1, allocate L2 (h panels; freshness via 12-deep slot
// rotation + aligned fence every 8 phases -- proven R7).
#define GLOAD16_C(gptr, lptr) \
  __builtin_amdgcn_global_load_lds((const __attribute__((address_space(1))) void*)(gptr), \
                                   (__attribute__((address_space(3))) void*)(lptr), 16, 0, 0)
#define GLOAD16_H(gptr, lptr) \
  __builtin_amdgcn_global_load_lds((const __attribute__((address_space(1))) void*)(gptr), \
                                   (__attribute__((address_space(3))) void*)(lptr), 16, 0, 0x1)

#define WAIT_VM10  asm volatile("s_waitcnt vmcnt(10)" ::: "memory")
#define WAIT_VM8   asm volatile("s_waitcnt vmcnt(8)"  ::: "memory")
#define WAIT_VM6   asm volatile("s_waitcnt vmcnt(6)"  ::: "memory")
#define WAIT_VM4   asm volatile("s_waitcnt vmcnt(4)"  ::: "memory")
#define WAIT_VM2   asm volatile("s_waitcnt vmcnt(2)"  ::: "memory")
#define WAIT_VM0   asm volatile("s_waitcnt vmcnt(0)"  ::: "memory")

__device__ __forceinline__ void wait_vm_chunks(int n) {   // n chunks (2 vm each) may stay outstanding
  if      (n <= 0) WAIT_VM0;
  else if (n == 1) WAIT_VM2;
  else if (n == 2) WAIT_VM4;
  else if (n == 3) WAIT_VM6;
  else if (n == 4) WAIT_VM8;
  else             WAIT_VM10;
}
__device__ __forceinline__ void wait_lgkm_n(int n) {      // n ds ops may stay outstanding
  if      (n <= 0)  asm volatile("s_waitcnt lgkmcnt(0)"  ::: "memory");
  else if (n <= 2)  asm volatile("s_waitcnt lgkmcnt(2)"  ::: "memory");
  else if (n <= 4)  asm volatile("s_waitcnt lgkmcnt(4)"  ::: "memory");
  else if (n <= 6)  asm volatile("s_waitcnt lgkmcnt(6)"  ::: "memory");
  else if (n <= 8)  asm volatile("s_waitcnt lgkmcnt(8)"  ::: "memory");
  else              asm volatile("s_waitcnt lgkmcnt(12)" ::: "memory");
}

__device__ __forceinline__ float sigm(float x)  { return 1.0f / (1.0f + __expf(-x)); }
__device__ __forceinline__ float tanhp(float x) { return 2.0f / (1.0f + __expf(-2.0f * x)) - 1.0f; }

// LLC-coherent scalar load / stores (bypass L1/L2)
__device__ __forceinline__ unsigned int coh_load(const unsigned int* p) {
  unsigned int v;
  asm volatile("global_load_dword %0, %1, off sc0 sc1\n\ts_waitcnt vmcnt(0)"
               : "=v"(v) : "v"(p) : "memory");
  return v;
}
__device__ __forceinline__ int coh_load_i(const int* p) {
  int v;
  asm volatile("global_load_dword %0, %1, off sc0 sc1\n\ts_waitcnt vmcnt(0)"
               : "=v"(v) : "v"(p) : "memory");
  return v;
}
__device__ __forceinline__ void coh_store16(void* p, bf16x8 v) {
  f32x4 f = *(f32x4*)&v;
  asm volatile("global_store_dwordx4 %0, %1, off sc0 sc1" :: "v"(p), "v"(f) : "memory");
}
__device__ __forceinline__ void flag_store(int* fp, int v) {
  asm volatile("global_store_dword %0, %1, off sc0 sc1" :: "v"(fp), "v"(v) : "memory");
}

#define TSTEPS 80
#define BATCH  512
#define EDIM   256
#define HDIM   512
#define K2     1024
#define K1     768
#define NCH    16           // B K-chunks in registers
#define D_SLOTS 12
#define SLOT_BYTES 524544   // 512 KB + 256 B guard
// LDS: BsL (16 chunks * 4KB = 64KB) | ring (8 * 8KB = 64KB) | epi (128 x 24 bf16)
#define RING_OFF 65536
#define EPI_OFF  131072
#define EPI_STR  24
#define LDS_BYTES 137216

struct Params {
  const __hip_bfloat16* Wz1t;   // [2048][768]  bf16, [N'][K], K-order [W1|U1] (x first)
  const __hip_bfloat16* Wz2t;   // [2048][1024]             K-order [W2|U2] (h1 first)
  const float* bz1;             // [2048] permuted
  const float* bz2;
  const __hip_bfloat16* Xall;   // [80][512][256] bf16
  char* h1base;                 // 12 slots, SLOT_BYTES stride
  char* h2base;                 // 12 slots
  int* flags;                   // 256 entries, 16B stride: z1 at idx, z2 at 128+idx
  const float* Wfc; const float* bfc;
  float* out;
};

// ---------------- prep kernels ----------------
// permuted column: n' = ntile*64 + gate*16 + u  (ntile = j>>4, u = j&15)
// K-order: the TIGHT-gated operand goes LAST:
//   Wz1t: k<256 -> W1[k] (x),  k>=256 -> U1[k-256] (h1[s-1], peer-gated)
//   Wz2t: k<512 -> W2[k] (h1), k>=512 -> U2[k-512] (h2[s-1], peer-gated)

__global__ __launch_bounds__(256) void prep_weights(
    const float* __restrict__ W1, const float* __restrict__ U1, const float* __restrict__ b1,
    const float* __restrict__ W2, const float* __restrict__ U2, const float* __restrict__ b2,
    __hip_bfloat16* __restrict__ Wz1t, __hip_bfloat16* __restrict__ Wz2t,
    float* __restrict__ bz1, float* __restrict__ bz2) {
  long idx = (long)blockIdx.x * 256 + threadIdx.x;
  const long n1 = 2048L * K1, n2 = 2048L * K2;
  if (idx < n1) {
    int n = (int)(idx / K1), k = (int)(idx % K1);
    int col = ((n >> 4) & 3) * 512 + (n >> 6) * 16 + (n & 15);
    float v = (k < 256) ? W1[(size_t)k * 2048 + col] : U1[(size_t)(k - 256) * 2048 + col];
    Wz1t[idx] = __float2bfloat16(v);
  } else if (idx < n1 + n2) {
    long r = idx - n1;
    int n = (int)(r / K2), k = (int)(r % K2);
    int col = ((n >> 4) & 3) * 512 + (n >> 6) * 16 + (n & 15);
    float v = (k < 512) ? W2[(size_t)k * 2048 + col] : U2[(size_t)(k - 512) * 2048 + col];
    Wz2t[r] = __float2bfloat16(v);
  } else if (idx < n1 + n2 + 2048) {
    int n = (int)(idx - (n1 + n2));
    bz1[n] = b1[((n >> 4) & 3) * 512 + (n >> 6) * 16 + (n & 15)];
  } else if (idx < n1 + n2 + 4096) {
    int n = (int)(idx - (n1 + n2 + 2048));
    bz2[n] = b2[((n >> 4) & 3) * 512 + (n >> 6) * 16 + (n & 15)];
  }
}

__global__ __launch_bounds__(256) void prep_gather(
    const int* __restrict__ tokens, const float* __restrict__ emb,
    __hip_bfloat16* __restrict__ Xall, float4* __restrict__ zp, int zn) {
  int idx = blockIdx.x * 256 + threadIdx.x;
  if (idx < zn) zp[idx] = make_float4(0.f, 0.f, 0.f, 0.f);   // zero state+flags
  int e  = (idx & 63) * 4;
  int rb = idx >> 6;            // t*512 + b
  int t  = rb >> 9;
  int b  = rb & 511;
  int tok = tokens[b * TSTEPS + t];
  const float4 v = *(const float4*)&emb[(size_t)tok * EDIM + e];
  __hip_bfloat16* o = Xall + (size_t)rb * EDIM + e;
  o[0] = __float2bfloat16(v.x); o[1] = __float2bfloat16(v.y);
  o[2] = __float2bfloat16(v.z); o[3] = __float2bfloat16(v.w);
}

// ---------------- main kernel ----------------
// R17 = R10 (proven 610us; gates/tail/fences/ring/NCH byte-identical) + ONE
// delta inside run_part: chunks are processed in PAIRS. One vmcnt wait + one
// batched fragment read + one lgkm wait serve TWO chunks, then 16 MFMAs run
// back-to-back. Why: R13-R16 falsified transport/window/traffic/TLP models;
// at 237ns/chunk vs ~130ns issue+compute, the residue is per-iteration wait
// quanta (32 vmcnt + 32 lgkm stall opportunities per z2 step at 1 wave/SIMD,
// where every stall is dead time). Pairing halves wait-points and doubles
// the MFMA run between stalls. Invariants preserved: lgkm allowance per pair
// = exactly the reads issued that pair (4 or 12, compile-time) so the
// previous pair's frags are retired before its slots are re-staged; vm
// allowance 2 chunks steady-state; fill-6 prologue; slot(kc+6)=slot(kc-2)
// whose reads retired one pair ago. Register cost +48 VGPR (~272 < 450
// spill line at 1 wave/SIMD; R15 ran clean at 252).

__device__ __forceinline__ void gate_wave(const int* flags, int base1, int t1,
                                          int base2, int t2, int lane) {
  const int idx = lane & 31;
  const int* fp = flags + (((lane < 32) ? base1 : base2) + idx) * 4;   // 16B stride
  const int tgt = (lane < 32) ? t1 : t2;
  for (;;) {
    int v = coh_load_i(fp);
    if (__ballot(v >= tgt) == ~0ull) break;
    __builtin_amdgcn_s_sleep(2);
  }
}

template<int K0, int LEN, int STRIDE, bool COH>
__device__ __forceinline__ void run_part(
    const __hip_bfloat16* __restrict__ Asrc, int m0, int w, int lane,
    __hip_bfloat16* __restrict__ ring, const __hip_bfloat16* __restrict__ BsL,
    const bf16x8 (&breg)[NCH][4], const int (&aoff)[2], const int (&boff)[4],
    f32x4 (&acc)[2][4]) {
  auto stage = [&](int kc) {
#pragma unroll
    for (int it = 0; it < 2; ++it) {
      const int gbase = w * 128 + it * 64;
      const int g   = gbase + lane;
      const int row = g >> 2;
      const int gc  = (g & 3) ^ ((row >> 1) & 3);       // XOR swizzle
      __hip_bfloat16* lp = ring + (kc & 7) * 4096 + gbase * 8;
      const __hip_bfloat16* gp = Asrc + (size_t)(m0 + row) * STRIDE + (kc - K0) * 32 + gc * 8;
      if (COH) GLOAD16_H(gp, lp); else GLOAD16_C(gp, lp);
    }
  };
#pragma unroll
  for (int f = 0; f < 6; ++f) stage(K0 + f);            // fill (LEN >= 8 always)

  // frags double-buffered by PAIR parity: af[par][chunk-in-pair][mi]
  bf16x8 af[2][2][2], bf[2][2][4];
  wait_vm_chunks(4);                                    // chunks K0,K0+1 resident
#pragma unroll
  for (int j = 0; j < 2; ++j) {
#pragma unroll
    for (int mi = 0; mi < 2; ++mi)
      af[0][j][mi] = *(const bf16x8*)(ring + ((K0 + j) & 7) * 4096 + aoff[mi]);
    if (K0 + j >= NCH)
#pragma unroll
      for (int g = 0; g < 4; ++g)
        bf[0][j][g] = *(const bf16x8*)(BsL + (K0 + j - NCH) * 2048 + boff[g]);
  }

#pragma unroll
  for (int p = 0; p < LEN / 2; ++p) {
    const int kc  = K0 + 2 * p;
    const int cur = p & 1, nxt = cur ^ 1;
    if (p + 1 < LEN / 2) {
      // chunks kc+2,kc+3 resident (steady state: 2 chunks may ride)
      { const int a = LEN - 4 - 2 * p; wait_vm_chunks(a < 2 ? (a < 0 ? 0 : a) : 2); }
      int nreads = 4;                                   // folds to a constant
#pragma unroll
      for (int j = 0; j < 2; ++j) {
        const int kn = kc + 2 + j;
#pragma unroll
        for (int mi = 0; mi < 2; ++mi)
          af[nxt][j][mi] = *(const bf16x8*)(ring + (kn & 7) * 4096 + aoff[mi]);
        if (kn >= NCH) {
#pragma unroll
          for (int g = 0; g < 4; ++g)
            bf[nxt][j][g] = *(const bf16x8*)(BsL + (kn - NCH) * 2048 + boff[g]);
          nreads += 4;
        }
      }
      wait_lgkm_n(nreads);              // prev pair's frags retired; ours in flight
      if (2 * p + 6 < LEN) stage(kc + 6);   // slot (kc-2): reads retired 1 pair ago
      if (2 * p + 7 < LEN) stage(kc + 7);   // slot (kc-1): ditto
    } else {
      wait_lgkm_n(0);
    }
#pragma unroll
    for (int j = 0; j < 2; ++j)
#pragma unroll
      for (int mi = 0; mi < 2; ++mi)
#pragma unroll
        for (int g = 0; g < 4; ++g)
          acc[mi][g] = __builtin_amdgcn_mfma_f32_16x16x32_bf16(
              af[cur][j][mi], (kc + j < NCH ? breg[kc + j][g] : bf[cur][j][g]),
              acc[mi][g], 0, 0, 0);
  }
}

template<bool Z2>
__device__ __forceinline__ void role_loop(const Params& p, char* smem, int tid,
                                          int grp, int ntile) {
  constexpr int K   = Z2 ? K2 : K1;
  constexpr int NC  = K / 32;
  const int lane = tid & 63;
  const int w    = tid >> 6;
  const int q    = lane >> 4;
  const int m16  = lane & 15;
  const int m0   = grp * 128;
  const int n0   = ntile * 64;

  __hip_bfloat16* BsL  = (__hip_bfloat16*)smem;
  __hip_bfloat16* ring = (__hip_bfloat16*)(smem + RING_OFF);
  __hip_bfloat16* epi  = (__hip_bfloat16*)(smem + EPI_OFF);

  const __hip_bfloat16* Bg = (Z2 ? p.Wz2t : p.Wz1t) + (size_t)n0 * K;

  // one-time: B chunks 0..NCH-1 into registers (static indexing only)
  bf16x8 breg[NCH][4];
#pragma unroll
  for (int kc = 0; kc < NCH; ++kc)
#pragma unroll
    for (int g = 0; g < 4; ++g)
      breg[kc][g] = *(const bf16x8*)(Bg + (size_t)(g * 16 + m16) * K + kc * 32 + q * 8);

  // one-time: B chunks NCH..NC-1 into LDS, chunk-major granule-swizzled
  for (int it0 = tid; it0 < (NC - NCH) * 256; it0 += 256) {
    int cid = it0 >> 8, gg = it0 & 255;
    int r = gg >> 2, c8 = gg & 3;
    int sw = c8 ^ ((r >> 1) & 3);
    *(bf16x8*)(BsL + cid * 2048 + r * 32 + sw * 8) =
        *(const bf16x8*)(Bg + (size_t)r * K + (NCH + cid) * 32 + c8 * 8);
  }
  const float* bias = Z2 ? p.bz2 : p.bz1;
  float bz[4];
#pragma unroll
  for (int g = 0; g < 4; ++g) bz[g] = bias[n0 + g * 16 + m16];

  const int swz = (q ^ ((m16 >> 1) & 3)) * 8;
  int aoff[2], boff[4];
#pragma unroll
  for (int mi = 0; mi < 2; ++mi) aoff[mi] = (w * 32 + mi * 16 + m16) * 32 + swz;
#pragma unroll
  for (int g = 0; g < 4; ++g)    boff[g]  = (g * 16 + m16) * 32 + swz;

  float cst[2][4] = {{0.f,0.f,0.f,0.f},{0.f,0.f,0.f,0.f}};
  const int fself = (Z2 ? 128 : 0) + grp * 32 + ntile;
  const int jbase = ntile * 16;
  __syncthreads();

  // pre-loop: z2's slack gate for step 0 (z1 >= 1 -> h1[0] committed)
  if (Z2) {
    if (w == 0) gate_wave(p.flags, grp * 32, 1, grp * 32, 1, lane);
    __syncthreads();
  }

  for (int s = 0; s < TSTEPS; ++s) {
    const int sl = s % D_SLOTS, slp = (s + D_SLOTS - 1) % D_SLOTS;
    const __hip_bfloat16* Aa = Z2
        ? (const __hip_bfloat16*)(p.h1base + (size_t)sl * SLOT_BYTES)    // h1[s]
        : p.Xall + (size_t)s * BATCH * EDIM;                             // x[s]
    const __hip_bfloat16* Ab = Z2
        ? (const __hip_bfloat16*)(p.h2base + (size_t)slp * SLOT_BYTES)   // h2[s-1]
        : (const __hip_bfloat16*)(p.h1base + (size_t)slp * SLOT_BYTES);  // h1[s-1]
    __hip_bfloat16* hout = (__hip_bfloat16*)
        ((Z2 ? p.h2base : p.h1base) + (size_t)sl * SLOT_BYTES);

    f32x4 acc[2][4];
#pragma unroll
    for (int mi = 0; mi < 2; ++mi)
#pragma unroll
      for (int g = 0; g < 4; ++g)
        acc[mi][g] = (f32x4){bz[g], bz[g], bz[g], bz[g]};

    // ---- part A (z2 slack gate already satisfied in previous tail) ----
    if (Z2) run_part<0, 16, 512, true >(Aa, m0, w, lane, ring, BsL, breg, aoff, boff, acc);
    else    run_part<0,  8, 256, false>(Aa, m0, w, lane, ring, BsL, breg, aoff, boff, acc);

    // ---- part B gate (tight peer RAW, hidden behind part A) + fence ----
    if (w == 0) {
      if (Z2) gate_wave(p.flags, 128 + grp * 32, s, 128 + grp * 32, s, lane);
      else    gate_wave(p.flags, grp * 32, s, 128 + grp * 32, s - (D_SLOTS - 1), lane);
      if ((s & 7) == 0) __builtin_amdgcn_fence(__ATOMIC_ACQUIRE, "agent");
    }
    __syncthreads();
    if (Z2) run_part<16, 16, 512, true>(Ab, m0, w, lane, ring, BsL, breg, aoff, boff, acc);
    else    run_part< 8, 16, 512, true>(Ab, m0, w, lane, ring, BsL, breg, aoff, boff, acc);

    // epilogue: gates -> cell state (regs) -> h via LDS transpose
#pragma unroll
    for (int mi = 0; mi < 2; ++mi)
#pragma unroll
      for (int rr = 0; rr < 4; ++rr) {
        const float zi = acc[mi][0][rr], zf = acc[mi][1][rr];
        const float zg = acc[mi][2][rr], zo = acc[mi][3][rr];
        const float cn = sigm(zf) * cst[mi][rr] + sigm(zi) * tanhp(zg);
        cst[mi][rr] = cn;
        epi[(w * 32 + mi * 16 + q * 4 + rr) * EPI_STR + m16] = __float2bfloat16(sigm(zo) * tanhp(cn));
      }
    __syncthreads();
    {
      const int r = tid >> 1, hf = tid & 1;
      bf16x8 hv = *(const bf16x8*)(epi + r * EPI_STR + hf * 8);
      coh_store16(hout + (size_t)(m0 + r) * HDIM + jbase + hf * 8, hv);
    }
    // z2: next step's slack gate polls here -- its vmcnt(0) subsumes the
    // store drain, so flag_store is not delayed. (z1 lead >= 2 in steady
    // state; startup transient only at s=0.)
    if (Z2 && w == 0 && s + 1 < TSTEPS)
      gate_wave(p.flags, grp * 32, s + 2, grp * 32, s + 2, lane);
    WAIT_VM0;                                      // h committed to LLC
    __syncthreads();
    if (tid == 0) flag_store(p.flags + fself * 4, s + 1);
  }
}

__global__ __launch_bounds__(256, 1) void lstm_seq(Params p) {
  extern __shared__ char smem[];
  const int tid = threadIdx.x;
  const bool z2  = ((blockIdx.x & 1) == 0);
  const int grp  = (blockIdx.x >> 1) & 3;
  const int ntile = blockIdx.x >> 3;

  if (z2) role_loop<true>(p, smem, tid, grp, ntile);
  else    role_loop<false>(p, smem, tid, grp, ntile);

  // final FC: block b -> rows {2b, 2b+1}; wait on producing z2 group's flags
  const int lane = tid & 63, w = tid >> 6;
  if (w == 0) {
    const int g2 = blockIdx.x >> 6;
    gate_wave(p.flags, 128 + g2 * 32, TSTEPS, 128 + g2 * 32, TSTEPS, lane);
  }
  __syncthreads();
  if (w < 2) {
    const int row = blockIdx.x * 2 + w;
    const unsigned int* hp = (const unsigned int*)
        (p.h2base + (size_t)((TSTEPS - 1) % D_SLOTS) * SLOT_BYTES) + (size_t)row * (HDIM / 2);
    float sum = 0.f;
#pragma unroll
    for (int cc = 0; cc < 4; ++cc) {
      unsigned int d = coh_load(hp + lane * 4 + cc);
      union { unsigned int ui; float f; } lo, hi;
      lo.ui = d << 16; hi.ui = d & 0xffff0000u;
      sum += lo.f * p.Wfc[(lane * 4 + cc) * 2] + hi.f * p.Wfc[(lane * 4 + cc) * 2 + 1];
    }
#pragma unroll
    for (int o = 32; o > 0; o >>= 1) sum += __shfl_down(sum, o, 64);
    if (lane == 0) p.out[row] = sigm(sum + p.bfc[0]);
  }
}

// ---------------- host launcher ----------------

extern "C" void kernel_launch(void* const* d_in, const int* in_sizes, int n_in,
                              void* d_out, int out_size, void* d_ws, size_t ws_size,
                              hipStream_t stream) {
  const int*   tokens = (const int*)d_in[0];
  const float* emb = (const float*)d_in[1];
  const float* W1  = (const float*)d_in[2];
  const float* U1  = (const float*)d_in[3];
  const float* b1  = (const float*)d_in[4];
  const float* W2  = (const float*)d_in[5];
  const float* U2  = (const float*)d_in[6];
  const float* b2  = (const float*)d_in[7];
  const float* Wfc = (const float*)d_in[8];
  const float* bfc = (const float*)d_in[9];

  char* ws = (char*)d_ws;
  size_t off = 0;
  auto alloc = [&](size_t bytes) {
    char* r = ws + off;
    off += (bytes + 255) & ~(size_t)255;
    return r;
  };
  __hip_bfloat16* Wz1t = (__hip_bfloat16*)alloc(2048UL * K1 * 2);
  __hip_bfloat16* Wz2t = (__hip_bfloat16*)alloc(2048UL * K2 * 2);
  float* bz1 = (float*)alloc(2048 * 4);
  float* bz2 = (float*)alloc(2048 * 4);
  __hip_bfloat16* Xall = (__hip_bfloat16*)alloc((size_t)TSTEPS * BATCH * EDIM * 2);
  // state: 24 h-slots (12 h1 + 12 h2) + flags (4096B), ALL zeroed in prep_gather
  const size_t state_bytes = 24UL * SLOT_BYTES + 4096;   // 12,593,152
  char* state = alloc(state_bytes);

  Params prm;
  prm.h1base = state;
  prm.h2base = state + 12UL * SLOT_BYTES;
  prm.flags  = (int*)(state + 24UL * SLOT_BYTES);

  prep_weights<<<dim3(14352), dim3(256), 0, stream>>>(W1, U1, b1, W2, U2, b2, Wz1t, Wz2t, bz1, bz2);
  prep_gather<<<dim3(10240), dim3(256), 0, stream>>>(tokens, emb, Xall,
                                                     (float4*)state, (int)(state_bytes / 16));

  hipFuncSetAttribute((const void*)lstm_seq,
                      hipFuncAttributeMaxDynamicSharedMemorySize, LDS_BYTES);

  prm.Wz1t = Wz1t; prm.Wz2t = Wz2t; prm.bz1 = bz1; prm.bz2 = bz2;
  prm.Xall = Xall;
  prm.Wfc = Wfc; prm.bfc = bfc;
  prm.out = (float*)d_out;

  lstm_seq<<<dim3(256), dim3(256), LDS_BYTES, stream>>>(prm);
}

// Round 12
// 688.928 us; speedup vs baseline: 1.1378x; 1.0704x over previous
//
#include <hip/hip_runtime.h>
#include <hip/hip_bf16.h>

typedef __bf16  bf16x8 __attribute__((ext_vector_type(8)));
typedef float   f32x4  __attribute__((ext_vector_type(4)));

// global->LDS async, 16B/lane. _C: fully cached (immutable X stream).
// _H: sc0 = bypass L1, allocate L2 (h panels; freshness via 12-deep slot
// rotation + aligned fence every 8 phases -- proven R7).
#define GLOAD16_C(gptr, lptr) \
  __builtin_amdgcn_global_load_lds((const __attribute__((address_space(1))) void*)(gptr), \
                                   (__attribute__((address_space(3))) void*)(lptr), 16, 0, 0)
#define GLOAD16_H(gptr, lptr) \
  __builtin_amdgcn_global_load_lds((const __attribute__((address_space(1))) void*)(gptr), \
                                   (__attribute__((address_space(3))) void*)(lptr), 16, 0, 0x1)

#define WAIT_VM10  asm volatile("s_waitcnt vmcnt(10)" ::: "memory")
#define WAIT_VM8   asm volatile("s_waitcnt vmcnt(8)"  ::: "memory")
#define WAIT_VM6   asm volatile("s_waitcnt vmcnt(6)"  ::: "memory")
#define WAIT_VM4   asm volatile("s_waitcnt vmcnt(4)"  ::: "memory")
#define WAIT_VM2   asm volatile("s_waitcnt vmcnt(2)"  ::: "memory")
#define WAIT_VM0   asm volatile("s_waitcnt vmcnt(0)"  ::: "memory")

__device__ __forceinline__ void wait_vm_chunks(int n) {   // n chunks (2 vm each) may stay outstanding
  if      (n <= 0) WAIT_VM0;
  else if (n == 1) WAIT_VM2;
  else if (n == 2) WAIT_VM4;
  else if (n == 3) WAIT_VM6;
  else if (n == 4) WAIT_VM8;
  else             WAIT_VM10;
}
__device__ __forceinline__ void wait_lgkm_n(int n) {
  if      (n <= 0) asm volatile("s_waitcnt lgkmcnt(0)" ::: "memory");
  else if (n <= 2) asm volatile("s_waitcnt lgkmcnt(2)" ::: "memory");
  else             asm volatile("s_waitcnt lgkmcnt(6)" ::: "memory");
}

__device__ __forceinline__ float sigm(float x)  { return 1.0f / (1.0f + __expf(-x)); }
__device__ __forceinline__ float tanhp(float x) { return 2.0f / (1.0f + __expf(-2.0f * x)) - 1.0f; }

// LLC-coherent scalar load / stores (bypass L1/L2)
__device__ __forceinline__ unsigned int coh_load(const unsigned int* p) {
  unsigned int v;
  asm volatile("global_load_dword %0, %1, off sc0 sc1\n\ts_waitcnt vmcnt(0)"
               : "=v"(v) : "v"(p) : "memory");
  return v;
}
__device__ __forceinline__ int coh_load_i(const int* p) {
  int v;
  asm volatile("global_load_dword %0, %1, off sc0 sc1\n\ts_waitcnt vmcnt(0)"
               : "=v"(v) : "v"(p) : "memory");
  return v;
}
__device__ __forceinline__ void coh_store16(void* p, bf16x8 v) {
  f32x4 f = *(f32x4*)&v;
  asm volatile("global_store_dwordx4 %0, %1, off sc0 sc1" :: "v"(p), "v"(f) : "memory");
}
__device__ __forceinline__ void flag_store(int* fp, int v) {
  asm volatile("global_store_dword %0, %1, off sc0 sc1" :: "v"(fp), "v"(v) : "memory");
}

#define TSTEPS 80
#define BATCH  512
#define EDIM   256
#define HDIM   512
#define K2     1024
#define K1     768
#define NCH    16           // B K-chunks in registers (256 VGPR; 1 wave/SIMD -> budget 512)
#define D_SLOTS 12
#define SLOT_BYTES 524544   // 512 KB + 256 B guard
// LDS: BsL (<=16 chunks * 4KB = 64KB) | ring (8 * 8KB = 64KB) | epi (128 x 24 bf16)
#define RING_OFF 65536
#define EPI_OFF  131072
#define EPI_STR  24
#define LDS_BYTES 137216

struct Params {
  const __hip_bfloat16* Wz1t;   // [2048][768]  bf16, [N'][K], K-order [W1|U1] (x first)
  const __hip_bfloat16* Wz2t;   // [2048][1024]             K-order [W2|U2] (h1 first)
  const float* bz1;             // [2048] permuted
  const float* bz2;
  const __hip_bfloat16* Xall;   // [80][512][256] bf16
  char* h1base;                 // 12 slots, SLOT_BYTES stride
  char* h2base;                 // 12 slots
  int* flags;                   // 256 entries, 16B stride: z1 at idx, z2 at 128+idx
  const float* Wfc; const float* bfc;
  float* out;
};

// ---------------- prep kernels ----------------
// permuted column: n' = ntile*64 + gate*16 + u  (ntile = j>>4, u = j&15)
// K-order: the TIGHT-gated operand goes LAST:
//   Wz1t: k<256 -> W1[k] (x),  k>=256 -> U1[k-256] (h1[s-1], peer-gated)
//   Wz2t: k<512 -> W2[k] (h1), k>=512 -> U2[k-512] (h2[s-1], peer-gated)

__global__ __launch_bounds__(256) void prep_weights(
    const float* __restrict__ W1, const float* __restrict__ U1, const float* __restrict__ b1,
    const float* __restrict__ W2, const float* __restrict__ U2, const float* __restrict__ b2,
    __hip_bfloat16* __restrict__ Wz1t, __hip_bfloat16* __restrict__ Wz2t,
    float* __restrict__ bz1, float* __restrict__ bz2) {
  long idx = (long)blockIdx.x * 256 + threadIdx.x;
  const long n1 = 2048L * K1, n2 = 2048L * K2;
  if (idx < n1) {
    int n = (int)(idx / K1), k = (int)(idx % K1);
    int col = ((n >> 4) & 3) * 512 + (n >> 6) * 16 + (n & 15);
    float v = (k < 256) ? W1[(size_t)k * 2048 + col] : U1[(size_t)(k - 256) * 2048 + col];
    Wz1t[idx] = __float2bfloat16(v);
  } else if (idx < n1 + n2) {
    long r = idx - n1;
    int n = (int)(r / K2), k = (int)(r % K2);
    int col = ((n >> 4) & 3) * 512 + (n >> 6) * 16 + (n & 15);
    float v = (k < 512) ? W2[(size_t)k * 2048 + col] : U2[(size_t)(k - 512) * 2048 + col];
    Wz2t[r] = __float2bfloat16(v);
  } else if (idx < n1 + n2 + 2048) {
    int n = (int)(idx - (n1 + n2));
    bz1[n] = b1[((n >> 4) & 3) * 512 + (n >> 6) * 16 + (n & 15)];
  } else if (idx < n1 + n2 + 4096) {
    int n = (int)(idx - (n1 + n2 + 2048));
    bz2[n] = b2[((n >> 4) & 3) * 512 + (n >> 6) * 16 + (n & 15)];
  }
}

__global__ __launch_bounds__(256) void prep_gather(
    const int* __restrict__ tokens, const float* __restrict__ emb,
    __hip_bfloat16* __restrict__ Xall, float4* __restrict__ zp, int zn) {
  int idx = blockIdx.x * 256 + threadIdx.x;
  if (idx < zn) zp[idx] = make_float4(0.f, 0.f, 0.f, 0.f);   // zero state+flags
  int e  = (idx & 63) * 4;
  int rb = idx >> 6;            // t*512 + b
  int t  = rb >> 9;
  int b  = rb & 511;
  int tok = tokens[b * TSTEPS + t];
  const float4 v = *(const float4*)&emb[(size_t)tok * EDIM + e];
  __hip_bfloat16* o = Xall + (size_t)rb * EDIM + e;
  o[0] = __float2bfloat16(v.x); o[1] = __float2bfloat16(v.y);
  o[2] = __float2bfloat16(v.z); o[3] = __float2bfloat16(v.w);
}

// ---------------- main kernel ----------------
// R19 = R10 (proven 610us; gates/tail/fences/ring/NCH byte-identical) + ONE
// isolated delta: the epilogue's FIRST __syncthreads is replaced with
// lgkmcnt(0). The epi transpose is wave-local -- wave w writes epi rows
// 32w..32w+31 (epi[(w*32+...)]) and reads exactly those rows back
// (r = tid>>1 maps tid 64w..64w+63 -> rows 32w..32w+31) -- so only the
// wave's own ds_writes must be retired before its ds_reads; no cross-wave
// ordering is needed. Removes one full-block barrier (+ its implicit
// all-counter drain) from the 80-step serial chain. This was observed in
// R8/R9 but never isolated on the R10 base (R8/R9 bundled it with
// regressions). Ledger: R8,R9,R11,R12,R13,R14,R16,R17 negative; R15 null;
// R10 best. If this is null too, R10 is the converged optimum of this
// inter-block protocol (latency-bound on the per-step serial chain).

__device__ __forceinline__ void gate_wave(const int* flags, int base1, int t1,
                                          int base2, int t2, int lane) {
  const int idx = lane & 31;
  const int* fp = flags + (((lane < 32) ? base1 : base2) + idx) * 4;   // 16B stride
  const int tgt = (lane < 32) ? t1 : t2;
  for (;;) {
    int v = coh_load_i(fp);
    if (__ballot(v >= tgt) == ~0ull) break;
    __builtin_amdgcn_s_sleep(2);
  }
}

template<int K0, int LEN, int STRIDE, bool COH>
__device__ __forceinline__ void run_part(
    const __hip_bfloat16* __restrict__ Asrc, int m0, int w, int lane,
    __hip_bfloat16* __restrict__ ring, const __hip_bfloat16* __restrict__ BsL,
    const bf16x8 (&breg)[NCH][4], const int (&aoff)[2], const int (&boff)[4],
    f32x4 (&acc)[2][4]) {
  auto stage = [&](int kc) {
#pragma unroll
    for (int it = 0; it < 2; ++it) {
      const int gbase = w * 128 + it * 64;
      const int g   = gbase + lane;
      const int row = g >> 2;
      const int gc  = (g & 3) ^ ((row >> 1) & 3);       // XOR swizzle
      __hip_bfloat16* lp = ring + (kc & 7) * 4096 + gbase * 8;
      const __hip_bfloat16* gp = Asrc + (size_t)(m0 + row) * STRIDE + (kc - K0) * 32 + gc * 8;
      if (COH) GLOAD16_H(gp, lp); else GLOAD16_C(gp, lp);
    }
  };
#pragma unroll
  for (int f = 0; f < 6; ++f) stage(K0 + f);            // fill (LEN >= 8 always)

  bf16x8 af[2][2], bf[2][4];
  wait_vm_chunks(5);                                    // chunk K0 resident
#pragma unroll
  for (int mi = 0; mi < 2; ++mi)
    af[0][mi] = *(const bf16x8*)(ring + (K0 & 7) * 4096 + aoff[mi]);
  if (K0 >= NCH)
#pragma unroll
    for (int g = 0; g < 4; ++g)
      bf[0][g] = *(const bf16x8*)(BsL + (K0 - NCH) * 2048 + boff[g]);

#pragma unroll
  for (int i = 0; i < LEN; ++i) {
    const int kc  = K0 + i;
    const int cur = i & 1, nxt = cur ^ 1;
    if (i + 1 < LEN) {
      wait_vm_chunks(LEN - 2 - i < 4 ? LEN - 2 - i : 4);   // chunk kc+1 resident
      const int kn = kc + 1;
#pragma unroll
      for (int mi = 0; mi < 2; ++mi)
        af[nxt][mi] = *(const bf16x8*)(ring + (kn & 7) * 4096 + aoff[mi]);
      if (kn >= NCH) {
#pragma unroll
        for (int g = 0; g < 4; ++g)
          bf[nxt][g] = *(const bf16x8*)(BsL + (kn - NCH) * 2048 + boff[g]);
        wait_lgkm_n(6);                 // frags of kc done; kc+1's 6 in flight
      } else {
        wait_lgkm_n(2);
      }
      if (i + 6 < LEN) stage(kc + 6);   // slot (kc+6)&7: read 2 iters ago -> free
    } else {
      wait_lgkm_n(0);
    }
#pragma unroll
    for (int mi = 0; mi < 2; ++mi)
#pragma unroll
      for (int g = 0; g < 4; ++g)
        acc[mi][g] = __builtin_amdgcn_mfma_f32_16x16x32_bf16(
            af[cur][mi], (kc < NCH ? breg[kc][g] : bf[cur][g]), acc[mi][g], 0, 0, 0);
  }
}

template<bool Z2>
__device__ __forceinline__ void role_loop(const Params& p, char* smem, int tid,
                                          int grp, int ntile) {
  constexpr int K   = Z2 ? K2 : K1;
  constexpr int NC  = K / 32;
  const int lane = tid & 63;
  const int w    = tid >> 6;
  const int q    = lane >> 4;
  const int m16  = lane & 15;
  const int m0   = grp * 128;
  const int n0   = ntile * 64;

  __hip_bfloat16* BsL  = (__hip_bfloat16*)smem;
  __hip_bfloat16* ring = (__hip_bfloat16*)(smem + RING_OFF);
  __hip_bfloat16* epi  = (__hip_bfloat16*)(smem + EPI_OFF);

  const __hip_bfloat16* Bg = (Z2 ? p.Wz2t : p.Wz1t) + (size_t)n0 * K;

  // one-time: B chunks 0..NCH-1 into registers (static indexing only)
  bf16x8 breg[NCH][4];
#pragma unroll
  for (int kc = 0; kc < NCH; ++kc)
#pragma unroll
    for (int g = 0; g < 4; ++g)
      breg[kc][g] = *(const bf16x8*)(Bg + (size_t)(g * 16 + m16) * K + kc * 32 + q * 8);

  // one-time: B chunks NCH..NC-1 into LDS, chunk-major granule-swizzled
  for (int it0 = tid; it0 < (NC - NCH) * 256; it0 += 256) {
    int cid = it0 >> 8, gg = it0 & 255;
    int r = gg >> 2, c8 = gg & 3;
    int sw = c8 ^ ((r >> 1) & 3);
    *(bf16x8*)(BsL + cid * 2048 + r * 32 + sw * 8) =
        *(const bf16x8*)(Bg + (size_t)r * K + (NCH + cid) * 32 + c8 * 8);
  }
  const float* bias = Z2 ? p.bz2 : p.bz1;
  float bz[4];
#pragma unroll
  for (int g = 0; g < 4; ++g) bz[g] = bias[n0 + g * 16 + m16];

  const int swz = (q ^ ((m16 >> 1) & 3)) * 8;
  int aoff[2], boff[4];
#pragma unroll
  for (int mi = 0; mi < 2; ++mi) aoff[mi] = (w * 32 + mi * 16 + m16) * 32 + swz;
#pragma unroll
  for (int g = 0; g < 4; ++g)    boff[g]  = (g * 16 + m16) * 32 + swz;

  float cst[2][4] = {{0.f,0.f,0.f,0.f},{0.f,0.f,0.f,0.f}};
  const int fself = (Z2 ? 128 : 0) + grp * 32 + ntile;
  const int jbase = ntile * 16;
  __syncthreads();

  // pre-loop: z2's slack gate for step 0 (z1 >= 1 -> h1[0] committed)
  if (Z2) {
    if (w == 0) gate_wave(p.flags, grp * 32, 1, grp * 32, 1, lane);
    __syncthreads();
  }

  for (int s = 0; s < TSTEPS; ++s) {
    const int sl = s % D_SLOTS, slp = (s + D_SLOTS - 1) % D_SLOTS;
    const __hip_bfloat16* Aa = Z2
        ? (const __hip_bfloat16*)(p.h1base + (size_t)sl * SLOT_BYTES)    // h1[s]
        : p.Xall + (size_t)s * BATCH * EDIM;                             // x[s]
    const __hip_bfloat16* Ab = Z2
        ? (const __hip_bfloat16*)(p.h2base + (size_t)slp * SLOT_BYTES)   // h2[s-1]
        : (const __hip_bfloat16*)(p.h1base + (size_t)slp * SLOT_BYTES);  // h1[s-1]
    __hip_bfloat16* hout = (__hip_bfloat16*)
        ((Z2 ? p.h2base : p.h1base) + (size_t)sl * SLOT_BYTES);

    f32x4 acc[2][4];
#pragma unroll
    for (int mi = 0; mi < 2; ++mi)
#pragma unroll
      for (int g = 0; g < 4; ++g)
        acc[mi][g] = (f32x4){bz[g], bz[g], bz[g], bz[g]};

    // ---- part A (z2 slack gate already satisfied in previous tail) ----
    if (Z2) run_part<0, 16, 512, true >(Aa, m0, w, lane, ring, BsL, breg, aoff, boff, acc);
    else    run_part<0,  8, 256, false>(Aa, m0, w, lane, ring, BsL, breg, aoff, boff, acc);

    // ---- part B gate (tight peer RAW, hidden behind part A) + fence ----
    if (w == 0) {
      if (Z2) gate_wave(p.flags, 128 + grp * 32, s, 128 + grp * 32, s, lane);
      else    gate_wave(p.flags, grp * 32, s, 128 + grp * 32, s - (D_SLOTS - 1), lane);
      if ((s & 7) == 0) __builtin_amdgcn_fence(__ATOMIC_ACQUIRE, "agent");
    }
    __syncthreads();
    if (Z2) run_part<16, 16, 512, true>(Ab, m0, w, lane, ring, BsL, breg, aoff, boff, acc);
    else    run_part< 8, 16, 512, true>(Ab, m0, w, lane, ring, BsL, breg, aoff, boff, acc);

    // epilogue: gates -> cell state (regs) -> h via LDS transpose.
    // Transpose is WAVE-LOCAL (wave w writes AND reads only epi rows
    // 32w..32w+31), so the wave's own lgkmcnt(0) suffices -- no barrier.
#pragma unroll
    for (int mi = 0; mi < 2; ++mi)
#pragma unroll
      for (int rr = 0; rr < 4; ++rr) {
        const float zi = acc[mi][0][rr], zf = acc[mi][1][rr];
        const float zg = acc[mi][2][rr], zo = acc[mi][3][rr];
        const float cn = sigm(zf) * cst[mi][rr] + sigm(zi) * tanhp(zg);
        cst[mi][rr] = cn;
        epi[(w * 32 + mi * 16 + q * 4 + rr) * EPI_STR + m16] = __float2bfloat16(sigm(zo) * tanhp(cn));
      }
    wait_lgkm_n(0);                                // wave-local transpose ready
    {
      const int r = tid >> 1, hf = tid & 1;
      bf16x8 hv = *(const bf16x8*)(epi + r * EPI_STR + hf * 8);
      coh_store16(hout + (size_t)(m0 + r) * HDIM + jbase + hf * 8, hv);
    }
    // z2: next step's slack gate polls here -- its vmcnt(0) subsumes the
    // store drain, so flag_store is not delayed. (z1 lead >= 2 in steady
    // state; startup transient only at s=0.)
    if (Z2 && w == 0 && s + 1 < TSTEPS)
      gate_wave(p.flags, grp * 32, s + 2, grp * 32, s + 2, lane);
    WAIT_VM0;                                      // h committed to LLC
    __syncthreads();
    if (tid == 0) flag_store(p.flags + fself * 4, s + 1);
  }
}

__global__ __launch_bounds__(256, 1) void lstm_seq(Params p) {
  extern __shared__ char smem[];
  const int tid = threadIdx.x;
  const bool z2  = ((blockIdx.x & 1) == 0);
  const int grp  = (blockIdx.x >> 1) & 3;
  const int ntile = blockIdx.x >> 3;

  if (z2) role_loop<true>(p, smem, tid, grp, ntile);
  else    role_loop<false>(p, smem, tid, grp, ntile);

  // final FC: block b -> rows {2b, 2b+1}; wait on producing z2 group's flags
  const int lane = tid & 63, w = tid >> 6;
  if (w == 0) {
    const int g2 = blockIdx.x >> 6;
    gate_wave(p.flags, 128 + g2 * 32, TSTEPS, 128 + g2 * 32, TSTEPS, lane);
  }
  __syncthreads();
  if (w < 2) {
    const int row = blockIdx.x * 2 + w;
    const unsigned int* hp = (const unsigned int*)
        (p.h2base + (size_t)((TSTEPS - 1) % D_SLOTS) * SLOT_BYTES) + (size_t)row * (HDIM / 2);
    float sum = 0.f;
#pragma unroll
    for (int cc = 0; cc < 4; ++cc) {
      unsigned int d = coh_load(hp + lane * 4 + cc);
      union { unsigned int ui; float f; } lo, hi;
      lo.ui = d << 16; hi.ui = d & 0xffff0000u;
      sum += lo.f * p.Wfc[(lane * 4 + cc) * 2] + hi.f * p.Wfc[(lane * 4 + cc) * 2 + 1];
    }
#pragma unroll
    for (int o = 32; o > 0; o >>= 1) sum += __shfl_down(sum, o, 64);
    if (lane == 0) p.out[row] = sigm(sum + p.bfc[0]);
  }
}

// ---------------- host launcher ----------------

extern "C" void kernel_launch(void* const* d_in, const int* in_sizes, int n_in,
                              void* d_out, int out_size, void* d_ws, size_t ws_size,
                              hipStream_t stream) {
  const int*   tokens = (const int*)d_in[0];
  const float* emb = (const float*)d_in[1];
  const float* W1  = (const float*)d_in[2];
  const float* U1  = (const float*)d_in[3];
  const float* b1  = (const float*)d_in[4];
  const float* W2  = (const float*)d_in[5];
  const float* U2  = (const float*)d_in[6];
  const float* b2  = (const float*)d_in[7];
  const float* Wfc = (const float*)d_in[8];
  const float* bfc = (const float*)d_in[9];

  char* ws = (char*)d_ws;
  size_t off = 0;
  auto alloc = [&](size_t bytes) {
    char* r = ws + off;
    off += (bytes + 255) & ~(size_t)255;
    return r;
  };
  __hip_bfloat16* Wz1t = (__hip_bfloat16*)alloc(2048UL * K1 * 2);
  __hip_bfloat16* Wz2t = (__hip_bfloat16*)alloc(2048UL * K2 * 2);
  float* bz1 = (float*)alloc(2048 * 4);
  float* bz2 = (float*)alloc(2048 * 4);
  __hip_bfloat16* Xall = (__hip_bfloat16*)alloc((size_t)TSTEPS * BATCH * EDIM * 2);
  // state: 24 h-slots (12 h1 + 12 h2) + flags (4096B), ALL zeroed in prep_gather
  const size_t state_bytes = 24UL * SLOT_BYTES + 4096;   // 12,593,152
  char* state = alloc(state_bytes);

  Params prm;
  prm.h1base = state;
  prm.h2base = state + 12UL * SLOT_BYTES;
  prm.flags  = (int*)(state + 24UL * SLOT_BYTES);

  prep_weights<<<dim3(14352), dim3(256), 0, stream>>>(W1, U1, b1, W2, U2, b2, Wz1t, Wz2t, bz1, bz2);
  prep_gather<<<dim3(10240), dim3(256), 0, stream>>>(tokens, emb, Xall,
                                                     (float4*)state, (int)(state_bytes / 16));

  hipFuncSetAttribute((const void*)lstm_seq,
                      hipFuncAttributeMaxDynamicSharedMemorySize, LDS_BYTES);

  prm.Wz1t = Wz1t; prm.Wz2t = Wz2t; prm.bz1 = bz1; prm.bz2 = bz2;
  prm.Xall = Xall;
  prm.Wfc = Wfc; prm.bfc = bfc;
  prm.out = (float*)d_out;

  lstm_seq<<<dim3(256), dim3(256), LDS_BYTES, stream>>>(prm);
}

// Round 13
// 682.356 us; speedup vs baseline: 1.1488x; 1.0096x over previous
//
#include <hip/hip_runtime.h>
#include <hip/hip_bf16.h>

typedef __bf16  bf16x8 __attribute__((ext_vector_type(8)));
typedef float   f32x4  __attribute__((ext_vector_type(4)));

// global->LDS async, 16B/lane. _C: fully cached (immutable X stream).
// _H: sc0 = bypass L1, allocate L2 (h panels; freshness via 12-deep slot
// rotation + aligned fence every 8 phases -- proven R7).
#define GLOAD16_C(gptr, lptr) \
  __builtin_amdgcn_global_load_lds((const __attribute__((address_space(1))) void*)(gptr), \
                                   (__attribute__((address_space(3))) void*)(lptr), 16, 0, 0)
#define GLOAD16_H(gptr, lptr) \
  __builtin_amdgcn_global_load_lds((const __attribute__((address_space(1))) void*)(gptr), \
                                   (__attribute__((address_space(3))) void*)(lptr), 16, 0, 0x1)

#define WAIT_VM10  asm volatile("s_waitcnt vmcnt(10)" ::: "memory")
#define WAIT_VM8   asm volatile("s_waitcnt vmcnt(8)"  ::: "memory")
#define WAIT_VM6   asm volatile("s_waitcnt vmcnt(6)"  ::: "memory")
#define WAIT_VM4   asm volatile("s_waitcnt vmcnt(4)"  ::: "memory")
#define WAIT_VM2   asm volatile("s_waitcnt vmcnt(2)"  ::: "memory")
#define WAIT_VM0   asm volatile("s_waitcnt vmcnt(0)"  ::: "memory")

__device__ __forceinline__ void wait_vm_chunks(int n) {   // n chunks (2 vm each) may stay outstanding
  if      (n <= 0) WAIT_VM0;
  else if (n == 1) WAIT_VM2;
  else if (n == 2) WAIT_VM4;
  else if (n == 3) WAIT_VM6;
  else if (n == 4) WAIT_VM8;
  else             WAIT_VM10;
}
__device__ __forceinline__ void wait_lgkm_n(int n) {
  if      (n <= 0) asm volatile("s_waitcnt lgkmcnt(0)" ::: "memory");
  else if (n <= 2) asm volatile("s_waitcnt lgkmcnt(2)" ::: "memory");
  else             asm volatile("s_waitcnt lgkmcnt(6)" ::: "memory");
}

__device__ __forceinline__ float sigm(float x)  { return 1.0f / (1.0f + __expf(-x)); }
__device__ __forceinline__ float tanhp(float x) { return 2.0f / (1.0f + __expf(-2.0f * x)) - 1.0f; }

// LLC-coherent scalar load / stores (bypass L1/L2)
__device__ __forceinline__ unsigned int coh_load(const unsigned int* p) {
  unsigned int v;
  asm volatile("global_load_dword %0, %1, off sc0 sc1\n\ts_waitcnt vmcnt(0)"
               : "=v"(v) : "v"(p) : "memory");
  return v;
}
__device__ __forceinline__ int coh_load_i(const int* p) {
  int v;
  asm volatile("global_load_dword %0, %1, off sc0 sc1\n\ts_waitcnt vmcnt(0)"
               : "=v"(v) : "v"(p) : "memory");
  return v;
}
__device__ __forceinline__ void coh_store16(void* p, bf16x8 v) {
  f32x4 f = *(f32x4*)&v;
  asm volatile("global_store_dwordx4 %0, %1, off sc0 sc1" :: "v"(p), "v"(f) : "memory");
}

#define TSTEPS 80
#define BATCH  512
#define EDIM   256
#define HDIM   512
#define K2     1024
#define K1     768
#define NCH    16           // B K-chunks in registers (256 VGPR; 1 wave/SIMD -> budget 512)
#define D_SLOTS 12
#define SLOT_BYTES 524544   // 512 KB + 256 B guard
// LDS: BsL (<=16 chunks * 4KB = 64KB) | ring (8 * 8KB = 64KB) | epi (128 x 24 bf16)
#define RING_OFF 65536
#define EPI_OFF  131072
#define EPI_STR  24
#define LDS_BYTES 137216

struct Params {
  const __hip_bfloat16* Wz1t;   // [2048][768]  bf16, [N'][K], K-order [W1|U1] (x first)
  const __hip_bfloat16* Wz2t;   // [2048][1024]             K-order [W2|U2] (h1 first)
  const float* bz1;             // [2048] permuted
  const float* bz2;
  const __hip_bfloat16* Xall;   // [80][512][256] bf16
  char* h1base;                 // 12 slots, SLOT_BYTES stride
  char* h2base;                 // 12 slots
  int* flags;                   // 256 counters, 16B stride: z1 at idx, z2 at 128+idx.
                                // R20: flag = WAVE-completion count (4 per block-step)
  const float* Wfc; const float* bfc;
  float* out;
};

// ---------------- prep kernels ----------------
// permuted column: n' = ntile*64 + gate*16 + u  (ntile = j>>4, u = j&15)
// K-order: the TIGHT-gated operand goes LAST:
//   Wz1t: k<256 -> W1[k] (x),  k>=256 -> U1[k-256] (h1[s-1], peer-gated)
//   Wz2t: k<512 -> W2[k] (h1), k>=512 -> U2[k-512] (h2[s-1], peer-gated)

__global__ __launch_bounds__(256) void prep_weights(
    const float* __restrict__ W1, const float* __restrict__ U1, const float* __restrict__ b1,
    const float* __restrict__ W2, const float* __restrict__ U2, const float* __restrict__ b2,
    __hip_bfloat16* __restrict__ Wz1t, __hip_bfloat16* __restrict__ Wz2t,
    float* __restrict__ bz1, float* __restrict__ bz2) {
  long idx = (long)blockIdx.x * 256 + threadIdx.x;
  const long n1 = 2048L * K1, n2 = 2048L * K2;
  if (idx < n1) {
    int n = (int)(idx / K1), k = (int)(idx % K1);
    int col = ((n >> 4) & 3) * 512 + (n >> 6) * 16 + (n & 15);
    float v = (k < 256) ? W1[(size_t)k * 2048 + col] : U1[(size_t)(k - 256) * 2048 + col];
    Wz1t[idx] = __float2bfloat16(v);
  } else if (idx < n1 + n2) {
    long r = idx - n1;
    int n = (int)(r / K2), k = (int)(r % K2);
    int col = ((n >> 4) & 3) * 512 + (n >> 6) * 16 + (n & 15);
    float v = (k < 512) ? W2[(size_t)k * 2048 + col] : U2[(size_t)(k - 512) * 2048 + col];
    Wz2t[r] = __float2bfloat16(v);
  } else if (idx < n1 + n2 + 2048) {
    int n = (int)(idx - (n1 + n2));
    bz1[n] = b1[((n >> 4) & 3) * 512 + (n >> 6) * 16 + (n & 15)];
  } else if (idx < n1 + n2 + 4096) {
    int n = (int)(idx - (n1 + n2 + 2048));
    bz2[n] = b2[((n >> 4) & 3) * 512 + (n >> 6) * 16 + (n & 15)];
  }
}

__global__ __launch_bounds__(256) void prep_gather(
    const int* __restrict__ tokens, const float* __restrict__ emb,
    __hip_bfloat16* __restrict__ Xall, float4* __restrict__ zp, int zn) {
  int idx = blockIdx.x * 256 + threadIdx.x;
  if (idx < zn) zp[idx] = make_float4(0.f, 0.f, 0.f, 0.f);   // zero state+flags
  int e  = (idx & 63) * 4;
  int rb = idx >> 6;            // t*512 + b
  int t  = rb >> 9;
  int b  = rb & 511;
  int tok = tokens[b * TSTEPS + t];
  const float4 v = *(const float4*)&emb[(size_t)tok * EDIM + e];
  __hip_bfloat16* o = Xall + (size_t)rb * EDIM + e;
  o[0] = __float2bfloat16(v.x); o[1] = __float2bfloat16(v.y);
  o[2] = __float2bfloat16(v.z); o[3] = __float2bfloat16(v.w);
}

// ---------------- main kernel ----------------
// R20 = R19 (607us: R10 + epilogue barrier->lgkm) + ONE delta: the FINAL
// per-step block barrier is removed. Mechanism (the only one that has ever
// won here -- R10, R19): delete serial-chain elements at the step boundary.
// The final barrier existed only to order all 4 waves' h-stores before the
// single block flag; everything else in the tail is wave-local (ring
// quarters, epi rows, cst). Replacement: flags become WAVE-completion
// counters -- each wave drains its OWN store (z2: the all-wave slack-gate
// poll's internal vmcnt(0); z1: WAIT_VM0) then atomicAdd(flag,1)
// (device-scope at LLC, m20). All gate targets scale x4. Safety: the
// mid-step gateB barrier bounds intra-block wave drift to <=1 step, so
// v >= 4t  <=>  all 4 waves completed step t (if any wave were at t-1,
// v <= 4t-1). Fast waves run ahead through epi/store/drain/next-fill and
// the jitter is absorbed at the gateB barrier behind part-A compute.
// Ledger: R8,R9,R11,R12,R13,R14,R16,R17 negative; R15 null; R10+R19 wins.

__device__ __forceinline__ void gate_wave(const int* flags, int base1, int t1,
                                          int base2, int t2, int lane) {
  const int idx = lane & 31;
  const int* fp = flags + (((lane < 32) ? base1 : base2) + idx) * 4;   // 16B stride
  const int tgt = (lane < 32) ? t1 : t2;
  for (;;) {
    int v = coh_load_i(fp);
    if (__ballot(v >= tgt) == ~0ull) break;
    __builtin_amdgcn_s_sleep(2);
  }
}

template<int K0, int LEN, int STRIDE, bool COH>
__device__ __forceinline__ void run_part(
    const __hip_bfloat16* __restrict__ Asrc, int m0, int w, int lane,
    __hip_bfloat16* __restrict__ ring, const __hip_bfloat16* __restrict__ BsL,
    const bf16x8 (&breg)[NCH][4], const int (&aoff)[2], const int (&boff)[4],
    f32x4 (&acc)[2][4]) {
  auto stage = [&](int kc) {
#pragma unroll
    for (int it = 0; it < 2; ++it) {
      const int gbase = w * 128 + it * 64;
      const int g   = gbase + lane;
      const int row = g >> 2;
      const int gc  = (g & 3) ^ ((row >> 1) & 3);       // XOR swizzle
      __hip_bfloat16* lp = ring + (kc & 7) * 4096 + gbase * 8;
      const __hip_bfloat16* gp = Asrc + (size_t)(m0 + row) * STRIDE + (kc - K0) * 32 + gc * 8;
      if (COH) GLOAD16_H(gp, lp); else GLOAD16_C(gp, lp);
    }
  };
#pragma unroll
  for (int f = 0; f < 6; ++f) stage(K0 + f);            // fill (LEN >= 8 always)

  bf16x8 af[2][2], bf[2][4];
  wait_vm_chunks(5);                                    // chunk K0 resident
#pragma unroll
  for (int mi = 0; mi < 2; ++mi)
    af[0][mi] = *(const bf16x8*)(ring + (K0 & 7) * 4096 + aoff[mi]);
  if (K0 >= NCH)
#pragma unroll
    for (int g = 0; g < 4; ++g)
      bf[0][g] = *(const bf16x8*)(BsL + (K0 - NCH) * 2048 + boff[g]);

#pragma unroll
  for (int i = 0; i < LEN; ++i) {
    const int kc  = K0 + i;
    const int cur = i & 1, nxt = cur ^ 1;
    if (i + 1 < LEN) {
      wait_vm_chunks(LEN - 2 - i < 4 ? LEN - 2 - i : 4);   // chunk kc+1 resident
      const int kn = kc + 1;
#pragma unroll
      for (int mi = 0; mi < 2; ++mi)
        af[nxt][mi] = *(const bf16x8*)(ring + (kn & 7) * 4096 + aoff[mi]);
      if (kn >= NCH) {
#pragma unroll
        for (int g = 0; g < 4; ++g)
          bf[nxt][g] = *(const bf16x8*)(BsL + (kn - NCH) * 2048 + boff[g]);
        wait_lgkm_n(6);                 // frags of kc done; kc+1's 6 in flight
      } else {
        wait_lgkm_n(2);
      }
      if (i + 6 < LEN) stage(kc + 6);   // slot (kc+6)&7: read 2 iters ago -> free
    } else {
      wait_lgkm_n(0);
    }
#pragma unroll
    for (int mi = 0; mi < 2; ++mi)
#pragma unroll
      for (int g = 0; g < 4; ++g)
        acc[mi][g] = __builtin_amdgcn_mfma_f32_16x16x32_bf16(
            af[cur][mi], (kc < NCH ? breg[kc][g] : bf[cur][g]), acc[mi][g], 0, 0, 0);
  }
}

template<bool Z2>
__device__ __forceinline__ void role_loop(const Params& p, char* smem, int tid,
                                          int grp, int ntile) {
  constexpr int K   = Z2 ? K2 : K1;
  constexpr int NC  = K / 32;
  const int lane = tid & 63;
  const int w    = tid >> 6;
  const int q    = lane >> 4;
  const int m16  = lane & 15;
  const int m0   = grp * 128;
  const int n0   = ntile * 64;

  __hip_bfloat16* BsL  = (__hip_bfloat16*)smem;
  __hip_bfloat16* ring = (__hip_bfloat16*)(smem + RING_OFF);
  __hip_bfloat16* epi  = (__hip_bfloat16*)(smem + EPI_OFF);

  const __hip_bfloat16* Bg = (Z2 ? p.Wz2t : p.Wz1t) + (size_t)n0 * K;

  // one-time: B chunks 0..NCH-1 into registers (static indexing only)
  bf16x8 breg[NCH][4];
#pragma unroll
  for (int kc = 0; kc < NCH; ++kc)
#pragma unroll
    for (int g = 0; g < 4; ++g)
      breg[kc][g] = *(const bf16x8*)(Bg + (size_t)(g * 16 + m16) * K + kc * 32 + q * 8);

  // one-time: B chunks NCH..NC-1 into LDS, chunk-major granule-swizzled
  for (int it0 = tid; it0 < (NC - NCH) * 256; it0 += 256) {
    int cid = it0 >> 8, gg = it0 & 255;
    int r = gg >> 2, c8 = gg & 3;
    int sw = c8 ^ ((r >> 1) & 3);
    *(bf16x8*)(BsL + cid * 2048 + r * 32 + sw * 8) =
        *(const bf16x8*)(Bg + (size_t)r * K + (NCH + cid) * 32 + c8 * 8);
  }
  const float* bias = Z2 ? p.bz2 : p.bz1;
  float bz[4];
#pragma unroll
  for (int g = 0; g < 4; ++g) bz[g] = bias[n0 + g * 16 + m16];

  const int swz = (q ^ ((m16 >> 1) & 3)) * 8;
  int aoff[2], boff[4];
#pragma unroll
  for (int mi = 0; mi < 2; ++mi) aoff[mi] = (w * 32 + mi * 16 + m16) * 32 + swz;
#pragma unroll
  for (int g = 0; g < 4; ++g)    boff[g]  = (g * 16 + m16) * 32 + swz;

  float cst[2][4] = {{0.f,0.f,0.f,0.f},{0.f,0.f,0.f,0.f}};
  int* fp_self = p.flags + ((Z2 ? 128 : 0) + grp * 32 + ntile) * 4;
  const int jbase = ntile * 16;
  __syncthreads();

  // pre-loop: z2's slack gate for step 0 (z1 >= 4 -> all h1[0] waves committed)
  if (Z2) {
    if (w == 0) gate_wave(p.flags, grp * 32, 4, grp * 32, 4, lane);
    __syncthreads();
  }

  for (int s = 0; s < TSTEPS; ++s) {
    const int sl = s % D_SLOTS, slp = (s + D_SLOTS - 1) % D_SLOTS;
    const __hip_bfloat16* Aa = Z2
        ? (const __hip_bfloat16*)(p.h1base + (size_t)sl * SLOT_BYTES)    // h1[s]
        : p.Xall + (size_t)s * BATCH * EDIM;                             // x[s]
    const __hip_bfloat16* Ab = Z2
        ? (const __hip_bfloat16*)(p.h2base + (size_t)slp * SLOT_BYTES)   // h2[s-1]
        : (const __hip_bfloat16*)(p.h1base + (size_t)slp * SLOT_BYTES);  // h1[s-1]
    __hip_bfloat16* hout = (__hip_bfloat16*)
        ((Z2 ? p.h2base : p.h1base) + (size_t)sl * SLOT_BYTES);

    f32x4 acc[2][4];
#pragma unroll
    for (int mi = 0; mi < 2; ++mi)
#pragma unroll
      for (int g = 0; g < 4; ++g)
        acc[mi][g] = (f32x4){bz[g], bz[g], bz[g], bz[g]};

    // ---- part A (z2 slack gate already satisfied in previous tail) ----
    if (Z2) run_part<0, 16, 512, true >(Aa, m0, w, lane, ring, BsL, breg, aoff, boff, acc);
    else    run_part<0,  8, 256, false>(Aa, m0, w, lane, ring, BsL, breg, aoff, boff, acc);

    // ---- part B gate (tight peer RAW, hidden behind part A) + fence ----
    if (w == 0) {
      if (Z2) gate_wave(p.flags, 128 + grp * 32, 4 * s, 128 + grp * 32, 4 * s, lane);
      else    gate_wave(p.flags, grp * 32, 4 * s, 128 + grp * 32, 4 * (s - (D_SLOTS - 1)), lane);
      if ((s & 7) == 0) __builtin_amdgcn_fence(__ATOMIC_ACQUIRE, "agent");
    }
    __syncthreads();
    if (Z2) run_part<16, 16, 512, true>(Ab, m0, w, lane, ring, BsL, breg, aoff, boff, acc);
    else    run_part< 8, 16, 512, true>(Ab, m0, w, lane, ring, BsL, breg, aoff, boff, acc);

    // epilogue: gates -> cell state (regs) -> h via LDS transpose.
    // Transpose is WAVE-LOCAL (wave w writes AND reads only epi rows
    // 32w..32w+31), so the wave's own lgkmcnt(0) suffices -- no barrier.
#pragma unroll
    for (int mi = 0; mi < 2; ++mi)
#pragma unroll
      for (int rr = 0; rr < 4; ++rr) {
        const float zi = acc[mi][0][rr], zf = acc[mi][1][rr];
        const float zg = acc[mi][2][rr], zo = acc[mi][3][rr];
        const float cn = sigm(zf) * cst[mi][rr] + sigm(zi) * tanhp(zg);
        cst[mi][rr] = cn;
        epi[(w * 32 + mi * 16 + q * 4 + rr) * EPI_STR + m16] = __float2bfloat16(sigm(zo) * tanhp(cn));
      }
    wait_lgkm_n(0);                                // wave-local transpose ready
    {
      const int r = tid >> 1, hf = tid & 1;
      bf16x8 hv = *(const bf16x8*)(epi + r * EPI_STR + hf * 8);
      coh_store16(hout + (size_t)(m0 + r) * HDIM + jbase + hf * 8, hv);
    }
    // ---- tail (no block barrier): each wave drains its OWN store, then
    // counts itself done. z2: the all-wave slack poll (z1 >= 4(s+2)) both
    // drains the store (internal vmcnt(0)) and licenses next-step h1 staging.
    if (Z2 && s + 1 < TSTEPS)
      gate_wave(p.flags, grp * 32, 4 * (s + 2), grp * 32, 4 * (s + 2), lane);
    else
      WAIT_VM0;                                    // z1 / final step: own drain
    if (lane == 0) atomicAdd(fp_self, 1);          // wave-completion count
  }
}

__global__ __launch_bounds__(256, 1) void lstm_seq(Params p) {
  extern __shared__ char smem[];
  const int tid = threadIdx.x;
  const bool z2  = ((blockIdx.x & 1) == 0);
  const int grp  = (blockIdx.x >> 1) & 3;
  const int ntile = blockIdx.x >> 3;

  if (z2) role_loop<true>(p, smem, tid, grp, ntile);
  else    role_loop<false>(p, smem, tid, grp, ntile);

  // final FC: block b -> rows {2b, 2b+1}; wait on producing z2 group's flags
  const int lane = tid & 63, w = tid >> 6;
  if (w == 0) {
    const int g2 = blockIdx.x >> 6;
    gate_wave(p.flags, 128 + g2 * 32, 4 * TSTEPS, 128 + g2 * 32, 4 * TSTEPS, lane);
  }
  __syncthreads();
  if (w < 2) {
    const int row = blockIdx.x * 2 + w;
    const unsigned int* hp = (const unsigned int*)
        (p.h2base + (size_t)((TSTEPS - 1) % D_SLOTS) * SLOT_BYTES) + (size_t)row * (HDIM / 2);
    float sum = 0.f;
#pragma unroll
    for (int cc = 0; cc < 4; ++cc) {
      unsigned int d = coh_load(hp + lane * 4 + cc);
      union { unsigned int ui; float f; } lo, hi;
      lo.ui = d << 16; hi.ui = d & 0xffff0000u;
      sum += lo.f * p.Wfc[(lane * 4 + cc) * 2] + hi.f * p.Wfc[(lane * 4 + cc) * 2 + 1];
    }
#pragma unroll
    for (int o = 32; o > 0; o >>= 1) sum += __shfl_down(sum, o, 64);
    if (lane == 0) p.out[row] = sigm(sum + p.bfc[0]);
  }
}

// ---------------- host launcher ----------------

extern "C" void kernel_launch(void* const* d_in, const int* in_sizes, int n_in,
                              void* d_out, int out_size, void* d_ws, size_t ws_size,
                              hipStream_t stream) {
  const int*   tokens = (const int*)d_in[0];
  const float* emb = (const float*)d_in[1];
  const float* W1  = (const float*)d_in[2];
  const float* U1  = (const float*)d_in[3];
  const float* b1  = (const float*)d_in[4];
  const float* W2  = (const float*)d_in[5];
  const float* U2  = (const float*)d_in[6];
  const float* b2  = (const float*)d_in[7];
  const float* Wfc = (const float*)d_in[8];
  const float* bfc = (const float*)d_in[9];

  char* ws = (char*)d_ws;
  size_t off = 0;
  auto alloc = [&](size_t bytes) {
    char* r = ws + off;
    off += (bytes + 255) & ~(size_t)255;
    return r;
  };
  __hip_bfloat16* Wz1t = (__hip_bfloat16*)alloc(2048UL * K1 * 2);
  __hip_bfloat16* Wz2t = (__hip_bfloat16*)alloc(2048UL * K2 * 2);
  float* bz1 = (float*)alloc(2048 * 4);
  float* bz2 = (float*)alloc(2048 * 4);
  __hip_bfloat16* Xall = (__hip_bfloat16*)alloc((size_t)TSTEPS * BATCH * EDIM * 2);
  // state: 24 h-slots (12 h1 + 12 h2) + flags (4096B), ALL zeroed in prep_gather
  const size_t state_bytes = 24UL * SLOT_BYTES + 4096;   // 12,593,152
  char* state = alloc(state_bytes);

  Params prm;
  prm.h1base = state;
  prm.h2base = state + 12UL * SLOT_BYTES;
  prm.flags  = (int*)(state + 24UL * SLOT_BYTES);

  prep_weights<<<dim3(14352), dim3(256), 0, stream>>>(W1, U1, b1, W2, U2, b2, Wz1t, Wz2t, bz1, bz2);
  prep_gather<<<dim3(10240), dim3(256), 0, stream>>>(tokens, emb, Xall,
                                                     (float4*)state, (int)(state_bytes / 16));

  hipFuncSetAttribute((const void*)lstm_seq,
                      hipFuncAttributeMaxDynamicSharedMemorySize, LDS_BYTES);

  prm.Wz1t = Wz1t; prm.Wz2t = Wz2t; prm.bz1 = bz1; prm.bz2 = bz2;
  prm.Xall = Xall;
  prm.Wfc = Wfc; prm.bfc = bfc;
  prm.out = (float*)d_out;

  lstm_seq<<<dim3(256), dim3(256), LDS_BYTES, stream>>>(prm);
}